// Round 13
// baseline (271.231 us; speedup 1.0000x reference)
//
#include <hip/hip_runtime.h>
#include <hip/hip_bf16.h>

typedef unsigned short u16;
typedef unsigned int   u32;

using bf8 = __attribute__((ext_vector_type(8))) __bf16;
using f4  = __attribute__((ext_vector_type(4))) float;

__device__ __forceinline__ float b2f(u16 u) {
    union { u32 i; float f; } v; v.i = ((u32)u) << 16; return v.f;
}
__device__ __forceinline__ u16 f2b(float f) {
    union { float f; u32 i; } v; v.f = f;
    u32 x = v.i;
    x += 0x7fffu + ((x >> 16) & 1u);   // RNE
    return (u16)(x >> 16);
}
// Packed fp32x2 -> bf16x2 (low = first arg).
__device__ __forceinline__ u32 pk2(float lo, float hi) {
    union { __hip_bfloat162 h; u32 u; } v;
    v.h = __float22bfloat162_rn(make_float2(lo, hi));
    return v.u;
}

// ---------------------------------------------------------------------------
// Direct weight-fragment load from row-major fp32 W (K x 256).
// Fragment element j <-> W[kbase + j][n]  (kbase = kt*32 + lg*8, n = ct*16+lr)
// Same values as the old swizzle path (pk2 = RNE) -> bit-identical MFMA input.
// ---------------------------------------------------------------------------
__device__ __forceinline__ bf8 ldwK(const float* __restrict__ W, int kbase, int n, int kmax) {
    union { u32 u[4]; bf8 v; } cv;
    #pragma unroll
    for (int jj = 0; jj < 4; ++jj) {
        int k0 = kbase + 2 * jj;
        float a = (k0     < kmax) ? W[(size_t)k0 * 256 + n]       : 0.f;
        float b = (k0 + 1 < kmax) ? W[(size_t)(k0 + 1) * 256 + n] : 0.f;
        cv.u[jj] = pk2(a, b);
    }
    return cv.v;
}
__device__ __forceinline__ bf8 ldw(const float* __restrict__ W, int kbase, int n) {
    union { u32 u[4]; bf8 v; } cv;
    #pragma unroll
    for (int jj = 0; jj < 4; ++jj) {
        float a = W[(size_t)(kbase + 2 * jj) * 256 + n];
        float b = W[(size_t)(kbase + 2 * jj + 1) * 256 + n];
        cv.u[jj] = pk2(a, b);
    }
    return cv.v;
}

// ---------------------------------------------------------------------------
// Fused critic (SINGLE kernel — the second graph node cost ~85 us fixed).
// r9 structure: operand-swapped MFMA, 32 batch rows/WG (96 phi rows),
// 256 threads, 4 waves, 4 hidden-tiles/wave, rt=6.
// A = weight frags (direct from fp32 global, L2/L3-resident),
// B = activations (LDS b128). C/D per lane: batch=lane&15, hidden=lg*4+reg
// -> contiguous b64 epilogues.
// LDS pool (u16): inp [0,6912) 96x72; h [6912,+96*264) stride 264.
// h reuse: S1 rows 0..31, S2 rows 32..63, RH0 rows 64..95, RH1 over S1.
// __launch_bounds__(256,2): min-waves=4 provably forces 64-VGPR spills
// (r8/r10); (256,2) -> 128 VGPRs, no spill (r9).
// ---------------------------------------------------------------------------
#define HS    264
#define H_OFF 6912
#define S2O   (32 * HS)
#define RH0O  (64 * HS)

__global__ __launch_bounds__(256, 2) void critic_kernel(
    const float* __restrict__ obs, const float* __restrict__ ag,
    const float* __restrict__ g,   const float* __restrict__ anchor,
    const float* __restrict__ act,
    const float* __restrict__ w1,  const float* __restrict__ b1,
    const float* __restrict__ w2,  const float* __restrict__ b2,
    const float* __restrict__ w3,  const float* __restrict__ b3,
    const float* __restrict__ w4,  const float* __restrict__ b4,
    const float* __restrict__ w5,  const float* __restrict__ b5,
    const float* __restrict__ w6,  const float* __restrict__ b6,
    const float* __restrict__ w7,  const float* __restrict__ b7,
    const float* __restrict__ w8,  const float* __restrict__ b8,
    float* __restrict__ out, int B) {

    __shared__ u16 pool[H_OFF + 96 * HS];   // 32256 u16 = 64512 B

    const int t    = threadIdx.x;
    const int lane = t & 63;
    const int wave = t >> 6;
    const int lr   = lane & 15;
    const int lg   = lane >> 4;
    const int wg   = blockIdx.x;
    const int kb0  = lg * 8;                // per-lane k base within 32-slice

    // ---- Gather: build pair inputs (96 rows x 54, pad to 64) ----
    if (t < 96) {
        const int O1[3] = {0, 0, 1}, O2[3] = {1, 2, 2};
        const int JA[3] = {3, 4, 6}, KA[3] = {5, 7, 8};
        int p = t / 32, bl = t % 32;
        int b = wg * 32 + bl;
        int j = JA[p], k = KA[p];
        bool sel = (anchor[b * 9 + j] - anchor[b * 9 + k]) >= 0.0f;
        int bit2 = sel ? j : k;
        int oi = sel ? O1[p] : O2[p];
        int oj = sel ? O2[p] : O1[p];
        u16* row = &pool[t * 72];
        row[0] = f2b(ag[b * 9 + p]);
        row[1] = f2b(ag[b * 9 + bit2]);
        row[2] = f2b(g[b * 9 + p]);
        row[3] = f2b(g[b * 9 + bit2]);
        for (int c = 0; c < 10; ++c) row[4 + c] = f2b(obs[b * 55 + c]);
        const u16 ONE = 0x3F80;
        row[14] = (oi == 0) ? ONE : 0; row[15] = (oi == 1) ? ONE : 0; row[16] = (oi == 2) ? ONE : 0;
        for (int c = 0; c < 15; ++c) row[17 + c] = f2b(obs[b * 55 + 10 + 15 * oi + c]);
        row[32] = (oj == 0) ? ONE : 0; row[33] = (oj == 1) ? ONE : 0; row[34] = (oj == 2) ? ONE : 0;
        for (int c = 0; c < 15; ++c) row[35 + c] = f2b(obs[b * 55 + 10 + 15 * oj + c]);
        for (int c = 0; c < 4; ++c)  row[50 + c] = f2b(act[b * 4 + c]);
        for (int c = 54; c < 64; ++c) row[c] = 0;
    }
    __syncthreads();

    u32 s1w[2][4][2];    // net0 pair-sums, packed bf16 (hidden-adjacent)
    u32 s2w[2][4][2];    // net1 pair-sums

    // ---- Phi networks (net 0: w1/w2, net 1: w3/w4) ----
    for (int net = 0; net < 2; ++net) {
        const float* W1f = net ? w3 : w1;
        const float* W2f = net ? w4 : w2;
        const float* bl1 = net ? b3 : b1;
        const float* bl2 = net ? b4 : b2;

        // Layer 1: A=W1^T frags (direct), B=inp rows (96 x 64 @ 64-k)
        f4 acc[6][4];
        #pragma unroll
        for (int rt = 0; rt < 6; ++rt)
            #pragma unroll
            for (int c = 0; c < 4; ++c) acc[rt][c] = (f4){0.f, 0.f, 0.f, 0.f};
        #pragma unroll
        for (int kt = 0; kt < 2; ++kt) {
            bf8 wfr[4];
            #pragma unroll
            for (int c = 0; c < 4; ++c)
                wfr[c] = ldwK(W1f, kt * 32 + kb0, (wave * 4 + c) * 16 + lr, 54);
            #pragma unroll
            for (int rt = 0; rt < 6; ++rt) {
                bf8 xfr = *(const bf8*)(&pool[(rt * 16 + lr) * 72 + kt * 32 + lg * 8]);
                #pragma unroll
                for (int c = 0; c < 4; ++c)
                    acc[rt][c] = __builtin_amdgcn_mfma_f32_16x16x32_bf16(wfr[c], xfr, acc[rt][c], 0, 0, 0);
            }
        }
        #pragma unroll
        for (int c = 0; c < 4; ++c) {
            float4 bv = *(const float4*)(bl1 + (wave * 4 + c) * 16 + lg * 4);
            #pragma unroll
            for (int rt = 0; rt < 6; ++rt) {
                uint2 w;
                w.x = pk2(fmaxf(acc[rt][c][0] + bv.x, 0.f), fmaxf(acc[rt][c][1] + bv.y, 0.f));
                w.y = pk2(fmaxf(acc[rt][c][2] + bv.z, 0.f), fmaxf(acc[rt][c][3] + bv.w, 0.f));
                *(uint2*)&pool[H_OFF + (rt * 16 + lr) * HS + (wave * 4 + c) * 16 + lg * 4] = w;
            }
        }
        __syncthreads();

        // Layer 2: A=W2^T frags (direct), B=h rows. Relu + pair-sum into regs.
        f4 acc2[6][4];
        #pragma unroll
        for (int rt = 0; rt < 6; ++rt)
            #pragma unroll
            for (int c = 0; c < 4; ++c) acc2[rt][c] = (f4){0.f, 0.f, 0.f, 0.f};
        #pragma unroll
        for (int ks = 0; ks < 8; ++ks) {
            bf8 wfr[4];
            #pragma unroll
            for (int c = 0; c < 4; ++c)
                wfr[c] = ldw(W2f, ks * 32 + kb0, (wave * 4 + c) * 16 + lr);
            #pragma unroll
            for (int rt = 0; rt < 6; ++rt) {
                bf8 hfr = *(const bf8*)(&pool[H_OFF + (rt * 16 + lr) * HS + ks * 32 + lg * 8]);
                #pragma unroll
                for (int c = 0; c < 4; ++c)
                    acc2[rt][c] = __builtin_amdgcn_mfma_f32_16x16x32_bf16(wfr[c], hfr, acc2[rt][c], 0, 0, 0);
            }
        }
        #pragma unroll
        for (int c = 0; c < 4; ++c) {
            float4 bv = *(const float4*)(bl2 + (wave * 4 + c) * 16 + lg * 4);
            #pragma unroll
            for (int s = 0; s < 2; ++s) {
                f4 sv = (f4){0.f, 0.f, 0.f, 0.f};
                #pragma unroll
                for (int p = 0; p < 3; ++p) {
                    sv[0] += fmaxf(acc2[p * 2 + s][c][0] + bv.x, 0.f);
                    sv[1] += fmaxf(acc2[p * 2 + s][c][1] + bv.y, 0.f);
                    sv[2] += fmaxf(acc2[p * 2 + s][c][2] + bv.z, 0.f);
                    sv[3] += fmaxf(acc2[p * 2 + s][c][3] + bv.w, 0.f);
                }
                if (net == 0) {
                    s1w[s][c][0] = pk2(sv[0], sv[1]);
                    s1w[s][c][1] = pk2(sv[2], sv[3]);
                } else {
                    s2w[s][c][0] = pk2(sv[0], sv[1]);
                    s2w[s][c][1] = pk2(sv[2], sv[3]);
                }
            }
        }
        __syncthreads();  // h reads done before next net overwrites h
    }

    // ---- Write S1 (rows 0..31), S2 (rows 32..63): one b64 each ----
    #pragma unroll
    for (int s = 0; s < 2; ++s)
        #pragma unroll
        for (int c = 0; c < 4; ++c) {
            int base = H_OFF + (s * 16 + lr) * HS + (wave * 4 + c) * 16 + lg * 4;
            *(uint2*)&pool[base]       = *(uint2*)&s1w[s][c][0];
            *(uint2*)&pool[base + S2O] = *(uint2*)&s2w[s][c][0];
        }
    __syncthreads();

    // ---- Rho hidden layers, both nets in one MFMA phase ----
    {
        f4 racc[4][4];
        #pragma unroll
        for (int rt = 0; rt < 4; ++rt)
            #pragma unroll
            for (int c = 0; c < 4; ++c) racc[rt][c] = (f4){0.f, 0.f, 0.f, 0.f};
        #pragma unroll
        for (int ks = 0; ks < 8; ++ks) {
            bf8 w5f[4], w7f[4];
            #pragma unroll
            for (int c = 0; c < 4; ++c) {
                int n = (wave * 4 + c) * 16 + lr;
                w5f[c] = ldw(w5, ks * 32 + kb0, n);
                w7f[c] = ldw(w7, ks * 32 + kb0, n);
            }
            #pragma unroll
            for (int rt = 0; rt < 2; ++rt) {
                bf8 s1f = *(const bf8*)(&pool[H_OFF + (rt * 16 + lr) * HS + ks * 32 + lg * 8]);
                bf8 s2f = *(const bf8*)(&pool[H_OFF + S2O + (rt * 16 + lr) * HS + ks * 32 + lg * 8]);
                #pragma unroll
                for (int c = 0; c < 4; ++c) {
                    racc[rt][c]     = __builtin_amdgcn_mfma_f32_16x16x32_bf16(w5f[c], s1f, racc[rt][c], 0, 0, 0);
                    racc[2 + rt][c] = __builtin_amdgcn_mfma_f32_16x16x32_bf16(w7f[c], s2f, racc[2 + rt][c], 0, 0, 0);
                }
            }
        }
        // net0 epilogue -> RH0 (rows 64..95; disjoint from S reads)
        #pragma unroll
        for (int c = 0; c < 4; ++c) {
            float4 bv = *(const float4*)(b5 + (wave * 4 + c) * 16 + lg * 4);
            #pragma unroll
            for (int rt = 0; rt < 2; ++rt) {
                uint2 w;
                w.x = pk2(fmaxf(racc[rt][c][0] + bv.x, 0.f), fmaxf(racc[rt][c][1] + bv.y, 0.f));
                w.y = pk2(fmaxf(racc[rt][c][2] + bv.z, 0.f), fmaxf(racc[rt][c][3] + bv.w, 0.f));
                *(uint2*)&pool[H_OFF + RH0O + (rt * 16 + lr) * HS + (wave * 4 + c) * 16 + lg * 4] = w;
            }
        }
        __syncthreads();   // all S1 reads done before net1 overwrites it
        // net1 epilogue -> RH1 (over consumed S1, rows 0..31)
        #pragma unroll
        for (int c = 0; c < 4; ++c) {
            float4 bv = *(const float4*)(b7 + (wave * 4 + c) * 16 + lg * 4);
            #pragma unroll
            for (int rt = 0; rt < 2; ++rt) {
                uint2 w;
                w.x = pk2(fmaxf(racc[2 + rt][c][0] + bv.x, 0.f), fmaxf(racc[2 + rt][c][1] + bv.y, 0.f));
                w.y = pk2(fmaxf(racc[2 + rt][c][2] + bv.z, 0.f), fmaxf(racc[2 + rt][c][3] + bv.w, 0.f));
                *(uint2*)&pool[H_OFF + (rt * 16 + lr) * HS + (wave * 4 + c) * 16 + lg * 4] = w;
            }
        }
        __syncthreads();
    }

    // ---- Final dots, split-K over 4 waves: q = rhoH @ w6 + b6. FP32 OUT ----
    {
        int net = lane >> 5, r = lane & 31;
        int hoff = net ? H_OFF : H_OFF + RH0O;
        const float* wv = net ? w8 : w6;
        float s = 0.f;
        int base = hoff + r * HS + wave * 64;
        #pragma unroll
        for (int it = 0; it < 16; ++it) {
            uint2 two = *(const uint2*)&pool[base + it * 4];
            float4 wq = *(const float4*)(wv + wave * 64 + it * 4);
            s += __uint_as_float(two.x << 16)          * wq.x;
            s += __uint_as_float(two.x & 0xffff0000u)  * wq.y;
            s += __uint_as_float(two.y << 16)          * wq.z;
            s += __uint_as_float(two.y & 0xffff0000u)  * wq.w;
        }
        ((u32*)pool)[t] = __float_as_uint(s);   // partials in dead inp region
    }
    __syncthreads();
    if (t < 64) {
        int net = t >> 5, r = t & 31;
        float qv = net ? b8[0] : b6[0];
        #pragma unroll
        for (int p = 0; p < 4; ++p)
            qv += __uint_as_float(((u32*)pool)[p * 64 + t]);
        out[net * B + wg * 32 + r] = qv;
    }
}

extern "C" void kernel_launch(void* const* d_in, const int* in_sizes, int n_in,
                              void* d_out, int out_size, void* d_ws, size_t ws_size,
                              hipStream_t stream) {
    const float* obs = (const float*)d_in[0];
    const float* ag  = (const float*)d_in[1];
    const float* g   = (const float*)d_in[2];
    const float* anc = (const float*)d_in[3];
    const float* act = (const float*)d_in[4];
    const float* w1  = (const float*)d_in[5];
    const float* b1  = (const float*)d_in[6];
    const float* w2  = (const float*)d_in[7];
    const float* b2  = (const float*)d_in[8];
    const float* w3  = (const float*)d_in[9];
    const float* b3  = (const float*)d_in[10];
    const float* w4  = (const float*)d_in[11];
    const float* b4  = (const float*)d_in[12];
    const float* w5  = (const float*)d_in[13];
    const float* b5  = (const float*)d_in[14];
    const float* w6  = (const float*)d_in[15];
    const float* b6  = (const float*)d_in[16];
    const float* w7  = (const float*)d_in[17];
    const float* b7  = (const float*)d_in[18];
    const float* w8  = (const float*)d_in[19];
    const float* b8  = (const float*)d_in[20];
    float* out = (float*)d_out;
    int B = in_sizes[0] / 55;

    critic_kernel<<<(B + 31) / 32, 256, 0, stream>>>(obs, ag, g, anc, act,
                                                     w1, b1, w2, b2, w3, b3, w4, b4,
                                                     w5, b5, w6, b6, w7, b7, w8, b8,
                                                     out, B);
}

// Round 14
// 215.241 us; speedup vs baseline: 1.2601x; 1.2601x over previous
//
#include <hip/hip_runtime.h>
#include <hip/hip_bf16.h>

typedef unsigned short u16;
typedef unsigned int   u32;

using bf8 = __attribute__((ext_vector_type(8))) __bf16;
using f4  = __attribute__((ext_vector_type(4))) float;

__device__ __forceinline__ u16 f2b(float f) {
    union { float f; u32 i; } v; v.f = f;
    u32 x = v.i;
    x += 0x7fffu + ((x >> 16) & 1u);   // RNE
    return (u16)(x >> 16);
}
// Packed fp32x2 -> bf16x2 (low = first arg).
__device__ __forceinline__ u32 pk2(float lo, float hi) {
    union { __hip_bfloat162 h; u32 u; } v;
    v.h = __float22bfloat162_rn(make_float2(lo, hi));
    return v.u;
}

// ---------------------------------------------------------------------------
// Weight swizzle (verified layout, unchanged from r9):
// dst[((kt*16+ct)*64+lane)*8+j] = bf16(W[kt*32+(lane>>4)*8+j][ct*16+(lane&15)])
// ---------------------------------------------------------------------------
__global__ void swz_all(const float* __restrict__ w1, const float* __restrict__ w3,
                        const float* __restrict__ w2, const float* __restrict__ w4,
                        const float* __restrict__ w5, const float* __restrict__ w7,
                        u16* __restrict__ ws) {
    __shared__ u16 slab[32 * 270];
    int b = blockIdx.x, t = threadIdx.x;
    const float* src; u16* dst; int kmax, kt;
    if      (b <  2) { src = w1; dst = ws;          kmax = 54;  kt = b;      }
    else if (b <  4) { src = w3; dst = ws + 16384;  kmax = 54;  kt = b - 2;  }
    else if (b < 12) { src = w2; dst = ws + 32768;  kmax = 256; kt = b - 4;  }
    else if (b < 20) { src = w4; dst = ws + 98304;  kmax = 256; kt = b - 12; }
    else if (b < 28) { src = w5; dst = ws + 163840; kmax = 256; kt = b - 20; }
    else             { src = w7; dst = ws + 229376; kmax = 256; kt = b - 28; }

    #pragma unroll
    for (int it = 0; it < 8; ++it) {
        int flat = it * 1024 + t * 4;
        int row = flat >> 8, col = flat & 255;
        int k = kt * 32 + row;
        float4 v = make_float4(0.f, 0.f, 0.f, 0.f);
        if (k < kmax) v = *(const float4*)(src + k * 256 + col);
        u32* sp = (u32*)&slab[row * 270 + col];
        sp[0] = pk2(v.x, v.y);
        sp[1] = pk2(v.z, v.w);
    }
    __syncthreads();

    int lane = t & 63, wave = t >> 6, lr = lane & 15, kg = lane >> 4;
    #pragma unroll
    for (int i = 0; i < 4; ++i) {
        int ct = wave * 4 + i;
        u16 v[8];
        #pragma unroll
        for (int j = 0; j < 8; ++j)
            v[j] = slab[(kg * 8 + j) * 270 + ct * 16 + lr];
        uint4 o;
        o.x = (u32)v[0] | ((u32)v[1] << 16);
        o.y = (u32)v[2] | ((u32)v[3] << 16);
        o.z = (u32)v[4] | ((u32)v[5] << 16);
        o.w = (u32)v[6] | ((u32)v[7] << 16);
        *(uint4*)(dst + (size_t)(((kt * 16 + ct) * 64 + lane) * 8)) = o;
    }
}

// ---------------------------------------------------------------------------
// Fused critic, r9 math with k-split L2 -> halved h LDS -> 3 blocks/CU.
// Operand-swapped MFMA (A=weight frags from ws/L2, B=activations LDS b128).
// C/D per lane: batch=lane&15, hidden=lg*4+reg -> contiguous b64 epilogues.
// 32 batch rows/WG, 256 thr, 4 waves. Per net: L1 half-a (hidden 0..127,
// wave tiles {2w,2w+1}) -> L2 ks0..3 -> L1 half-b (tiles {8+2w,9+2w}) ->
// L2 ks4..7; acc2[6][4] persists in regs across halves.
// LDS pool (u16): inp [0,6912) 96x72; h-half [6912,19968) 96x136.
// Post-phi overlay (inp+h dead): S1 rows0..31 @ [0,..) stride 264,
// S2 @ +8448; RH overwrites S after rho; partials u32[8448..8704).
// 39936 B/WG. __launch_bounds__(256,2): min-waves>=4 forces 64-VGPR spills
// (r8/r10); (256,2) -> no spill, VGPR ~150 -> 3 waves/SIMD -> 3 blocks/CU.
// ---------------------------------------------------------------------------
#define HS2   136
#define H_OFF 6912
#define SS    264
#define S2OFF 8448
#define PART32 8448

__global__ __launch_bounds__(256, 2) void critic_kernel(
    const float* __restrict__ obs, const float* __restrict__ ag,
    const float* __restrict__ g,   const float* __restrict__ anchor,
    const float* __restrict__ act,
    const float* __restrict__ b1,  const float* __restrict__ b2,
    const float* __restrict__ b3,  const float* __restrict__ b4,
    const float* __restrict__ b5,  const float* __restrict__ b7,
    const float* __restrict__ w6,  const float* __restrict__ b6,
    const float* __restrict__ w8,  const float* __restrict__ b8,
    const u16* __restrict__ wsz, float* __restrict__ out, int B) {

    __shared__ __align__(16) u16 pool[19968];   // 39936 B

    const int t    = threadIdx.x;
    const int lane = t & 63;
    const int wave = t >> 6;
    const int lr   = lane & 15;
    const int lg   = lane >> 4;
    const int wg   = blockIdx.x;

    // ---- Gather: build pair inputs (96 rows x 54, pad to 64) ----
    if (t < 96) {
        const int O1[3] = {0, 0, 1}, O2[3] = {1, 2, 2};
        const int JA[3] = {3, 4, 6}, KA[3] = {5, 7, 8};
        int p = t / 32, bl = t % 32;
        int b = wg * 32 + bl;
        int j = JA[p], k = KA[p];
        bool sel = (anchor[b * 9 + j] - anchor[b * 9 + k]) >= 0.0f;
        int bit2 = sel ? j : k;
        int oi = sel ? O1[p] : O2[p];
        int oj = sel ? O2[p] : O1[p];
        u16* row = &pool[t * 72];
        row[0] = f2b(ag[b * 9 + p]);
        row[1] = f2b(ag[b * 9 + bit2]);
        row[2] = f2b(g[b * 9 + p]);
        row[3] = f2b(g[b * 9 + bit2]);
        for (int c = 0; c < 10; ++c) row[4 + c] = f2b(obs[b * 55 + c]);
        const u16 ONE = 0x3F80;
        row[14] = (oi == 0) ? ONE : 0; row[15] = (oi == 1) ? ONE : 0; row[16] = (oi == 2) ? ONE : 0;
        for (int c = 0; c < 15; ++c) row[17 + c] = f2b(obs[b * 55 + 10 + 15 * oi + c]);
        row[32] = (oj == 0) ? ONE : 0; row[33] = (oj == 1) ? ONE : 0; row[34] = (oj == 2) ? ONE : 0;
        for (int c = 0; c < 15; ++c) row[35 + c] = f2b(obs[b * 55 + 10 + 15 * oj + c]);
        for (int c = 0; c < 4; ++c)  row[50 + c] = f2b(act[b * 4 + c]);
        for (int c = 54; c < 64; ++c) row[c] = 0;
    }
    __syncthreads();

    u32 s1w[2][4][2];    // net0 pair-sums, packed bf16 (hidden-adjacent)
    u32 s2w[2][4][2];    // net1 pair-sums

    // ---- Phi networks ----
    for (int net = 0; net < 2; ++net) {
        const u16* Wl1 = wsz + (net ? 16384 : 0);
        const u16* Wl2 = wsz + 32768 + (net ? 65536 : 0);
        const float* bl1 = net ? b3 : b1;
        const float* bl2 = net ? b4 : b2;

        f4 acc2[6][4];
        #pragma unroll
        for (int rt = 0; rt < 6; ++rt)
            #pragma unroll
            for (int c = 0; c < 4; ++c) acc2[rt][c] = (f4){0.f, 0.f, 0.f, 0.f};

        #pragma unroll
        for (int half = 0; half < 2; ++half) {
            // -- L1 half: hidden tiles tb, tb+1 (tb = half*8 + wave*2) --
            {
                int tb = half * 8 + wave * 2;
                bf8 wfr[2][2];
                #pragma unroll
                for (int kt = 0; kt < 2; ++kt)
                    #pragma unroll
                    for (int cc = 0; cc < 2; ++cc)
                        wfr[kt][cc] = *(const bf8*)(Wl1 + (size_t)(((kt * 16 + tb + cc) * 64 + lane) * 8));
                float4 bv0 = *(const float4*)(bl1 + (tb + 0) * 16 + lg * 4);
                float4 bv1 = *(const float4*)(bl1 + (tb + 1) * 16 + lg * 4);
                #pragma unroll
                for (int rt = 0; rt < 6; ++rt) {
                    f4 a0 = (f4){0.f, 0.f, 0.f, 0.f};
                    f4 a1 = (f4){0.f, 0.f, 0.f, 0.f};
                    #pragma unroll
                    for (int kt = 0; kt < 2; ++kt) {
                        bf8 xfr = *(const bf8*)(&pool[(rt * 16 + lr) * 72 + kt * 32 + lg * 8]);
                        a0 = __builtin_amdgcn_mfma_f32_16x16x32_bf16(wfr[kt][0], xfr, a0, 0, 0, 0);
                        a1 = __builtin_amdgcn_mfma_f32_16x16x32_bf16(wfr[kt][1], xfr, a1, 0, 0, 0);
                    }
                    uint2 w0, w1;
                    w0.x = pk2(fmaxf(a0[0] + bv0.x, 0.f), fmaxf(a0[1] + bv0.y, 0.f));
                    w0.y = pk2(fmaxf(a0[2] + bv0.z, 0.f), fmaxf(a0[3] + bv0.w, 0.f));
                    w1.x = pk2(fmaxf(a1[0] + bv1.x, 0.f), fmaxf(a1[1] + bv1.y, 0.f));
                    w1.y = pk2(fmaxf(a1[2] + bv1.z, 0.f), fmaxf(a1[3] + bv1.w, 0.f));
                    int rb = H_OFF + (rt * 16 + lr) * HS2 + lg * 4;
                    *(uint2*)&pool[rb + (wave * 2 + 0) * 16] = w0;
                    *(uint2*)&pool[rb + (wave * 2 + 1) * 16] = w1;
                }
            }
            __syncthreads();

            // -- L2 quarter: ks = half*4 .. half*4+3 (h-local k4 = 0..3) --
            #pragma unroll
            for (int k4 = 0; k4 < 4; ++k4) {
                int ks = half * 4 + k4;
                bf8 wfr2[4];
                #pragma unroll
                for (int c = 0; c < 4; ++c)
                    wfr2[c] = *(const bf8*)(Wl2 + (size_t)(((ks * 16 + wave * 4 + c) * 64 + lane) * 8));
                #pragma unroll
                for (int rt = 0; rt < 6; ++rt) {
                    bf8 hfr = *(const bf8*)(&pool[H_OFF + (rt * 16 + lr) * HS2 + k4 * 32 + lg * 8]);
                    #pragma unroll
                    for (int c = 0; c < 4; ++c)
                        acc2[rt][c] = __builtin_amdgcn_mfma_f32_16x16x32_bf16(wfr2[c], hfr, acc2[rt][c], 0, 0, 0);
                }
            }
            __syncthreads();   // h reads done before overwrite (next half / net / S)
        }

        // -- pair-sum epilogue (rt = p*2+s -> batch row s*16+lr) --
        #pragma unroll
        for (int c = 0; c < 4; ++c) {
            float4 bv = *(const float4*)(bl2 + (wave * 4 + c) * 16 + lg * 4);
            #pragma unroll
            for (int s = 0; s < 2; ++s) {
                f4 sv = (f4){0.f, 0.f, 0.f, 0.f};
                #pragma unroll
                for (int p = 0; p < 3; ++p) {
                    sv[0] += fmaxf(acc2[p * 2 + s][c][0] + bv.x, 0.f);
                    sv[1] += fmaxf(acc2[p * 2 + s][c][1] + bv.y, 0.f);
                    sv[2] += fmaxf(acc2[p * 2 + s][c][2] + bv.z, 0.f);
                    sv[3] += fmaxf(acc2[p * 2 + s][c][3] + bv.w, 0.f);
                }
                if (net == 0) {
                    s1w[s][c][0] = pk2(sv[0], sv[1]);
                    s1w[s][c][1] = pk2(sv[2], sv[3]);
                } else {
                    s2w[s][c][0] = pk2(sv[0], sv[1]);
                    s2w[s][c][1] = pk2(sv[2], sv[3]);
                }
            }
        }
    }

    // ---- Write S1 (rows 0..31 @ pool[0], stride 264), S2 (@ +8448) ----
    // inp and h are both dead here (trailing barrier of half-loop passed).
    #pragma unroll
    for (int s = 0; s < 2; ++s)
        #pragma unroll
        for (int c = 0; c < 4; ++c) {
            int base = (s * 16 + lr) * SS + (wave * 4 + c) * 16 + lg * 4;
            *(uint2*)&pool[base]         = *(uint2*)&s1w[s][c][0];
            *(uint2*)&pool[base + S2OFF] = *(uint2*)&s2w[s][c][0];
        }
    __syncthreads();

    // ---- Rho hidden layers, both nets in one MFMA phase ----
    {
        const u16* W5 = wsz + 163840;
        const u16* W7 = wsz + 229376;
        f4 racc[4][4];
        #pragma unroll
        for (int rt = 0; rt < 4; ++rt)
            #pragma unroll
            for (int c = 0; c < 4; ++c) racc[rt][c] = (f4){0.f, 0.f, 0.f, 0.f};
        #pragma unroll
        for (int ks = 0; ks < 8; ++ks) {
            bf8 w5f[4], w7f[4];
            #pragma unroll
            for (int c = 0; c < 4; ++c) {
                size_t off = (size_t)(((ks * 16 + wave * 4 + c) * 64 + lane) * 8);
                w5f[c] = *(const bf8*)(W5 + off);
                w7f[c] = *(const bf8*)(W7 + off);
            }
            #pragma unroll
            for (int rt = 0; rt < 2; ++rt) {
                bf8 s1f = *(const bf8*)(&pool[(rt * 16 + lr) * SS + ks * 32 + lg * 8]);
                bf8 s2f = *(const bf8*)(&pool[S2OFF + (rt * 16 + lr) * SS + ks * 32 + lg * 8]);
                #pragma unroll
                for (int c = 0; c < 4; ++c) {
                    racc[rt][c]     = __builtin_amdgcn_mfma_f32_16x16x32_bf16(w5f[c], s1f, racc[rt][c], 0, 0, 0);
                    racc[2 + rt][c] = __builtin_amdgcn_mfma_f32_16x16x32_bf16(w7f[c], s2f, racc[2 + rt][c], 0, 0, 0);
                }
            }
        }
        __syncthreads();   // all S reads done before RH overwrites S

        // RH0 over S1 rows, RH1 over S2 rows
        #pragma unroll
        for (int c = 0; c < 4; ++c) {
            float4 bv5 = *(const float4*)(b5 + (wave * 4 + c) * 16 + lg * 4);
            float4 bv7 = *(const float4*)(b7 + (wave * 4 + c) * 16 + lg * 4);
            #pragma unroll
            for (int rt = 0; rt < 2; ++rt) {
                uint2 w0, w1;
                w0.x = pk2(fmaxf(racc[rt][c][0] + bv5.x, 0.f), fmaxf(racc[rt][c][1] + bv5.y, 0.f));
                w0.y = pk2(fmaxf(racc[rt][c][2] + bv5.z, 0.f), fmaxf(racc[rt][c][3] + bv5.w, 0.f));
                w1.x = pk2(fmaxf(racc[2 + rt][c][0] + bv7.x, 0.f), fmaxf(racc[2 + rt][c][1] + bv7.y, 0.f));
                w1.y = pk2(fmaxf(racc[2 + rt][c][2] + bv7.z, 0.f), fmaxf(racc[2 + rt][c][3] + bv7.w, 0.f));
                int base = (rt * 16 + lr) * SS + (wave * 4 + c) * 16 + lg * 4;
                *(uint2*)&pool[base]         = w0;
                *(uint2*)&pool[base + S2OFF] = w1;
            }
        }
        __syncthreads();
    }

    // ---- Final dots, split-K over 4 waves. FP32 OUT ----
    {
        int net = lane >> 5, r = lane & 31;
        int hoff = net ? S2OFF : 0;
        const float* wv = net ? w8 : w6;
        float s = 0.f;
        int base = hoff + r * SS + wave * 64;
        #pragma unroll
        for (int it = 0; it < 16; ++it) {
            uint2 two = *(const uint2*)&pool[base + it * 4];
            float4 wq = *(const float4*)(wv + wave * 64 + it * 4);
            s += __uint_as_float(two.x << 16)          * wq.x;
            s += __uint_as_float(two.x & 0xffff0000u)  * wq.y;
            s += __uint_as_float(two.y << 16)          * wq.z;
            s += __uint_as_float(two.y & 0xffff0000u)  * wq.w;
        }
        ((u32*)pool)[PART32 + t] = __float_as_uint(s);   // tail gap, disjoint from RH
    }
    __syncthreads();
    if (t < 64) {
        int net = t >> 5, r = t & 31;
        float qv = net ? b8[0] : b6[0];
        #pragma unroll
        for (int p = 0; p < 4; ++p)
            qv += __uint_as_float(((u32*)pool)[PART32 + p * 64 + t]);
        out[net * B + wg * 32 + r] = qv;
    }
}

extern "C" void kernel_launch(void* const* d_in, const int* in_sizes, int n_in,
                              void* d_out, int out_size, void* d_ws, size_t ws_size,
                              hipStream_t stream) {
    const float* obs = (const float*)d_in[0];
    const float* ag  = (const float*)d_in[1];
    const float* g   = (const float*)d_in[2];
    const float* anc = (const float*)d_in[3];
    const float* act = (const float*)d_in[4];
    const float* w1  = (const float*)d_in[5];
    const float* b1  = (const float*)d_in[6];
    const float* w2  = (const float*)d_in[7];
    const float* b2  = (const float*)d_in[8];
    const float* w3  = (const float*)d_in[9];
    const float* b3  = (const float*)d_in[10];
    const float* w4  = (const float*)d_in[11];
    const float* b4  = (const float*)d_in[12];
    const float* w5  = (const float*)d_in[13];
    const float* b5  = (const float*)d_in[14];
    const float* w6  = (const float*)d_in[15];
    const float* b6  = (const float*)d_in[16];
    const float* w7  = (const float*)d_in[17];
    const float* b7  = (const float*)d_in[18];
    const float* w8  = (const float*)d_in[19];
    const float* b8  = (const float*)d_in[20];
    u16* ws    = (u16*)d_ws;
    float* out = (float*)d_out;
    int B = in_sizes[0] / 55;

    swz_all<<<36, 256, 0, stream>>>(w1, w3, w2, w4, w5, w7, ws);
    critic_kernel<<<(B + 31) / 32, 256, 0, stream>>>(obs, ag, g, anc, act,
                                                     b1, b2, b3, b4, b5, b7,
                                                     w6, b6, w8, b8, ws, out, B);
}